// Round 17
// baseline (118.540 us; speedup 1.0000x reference)
//
#include <hip/hip_runtime.h>

#define T_SEQ 8192
#define BATCH 2
#define DMODEL 2048
#define NHEADS 8
#define DH 256
#define NROWS (BATCH * T_SEQ)  // 16384

typedef __attribute__((ext_vector_type(8))) short short8;
typedef __attribute__((ext_vector_type(4))) short short4v;
typedef __attribute__((ext_vector_type(4))) float f32x4;

static __device__ __forceinline__ unsigned short f2bf(float f) {
  unsigned u = __float_as_uint(f);
  unsigned r = u + 0x7FFFu + ((u >> 16) & 1u);  // RNE
  return (unsigned short)(r >> 16);
}

static __device__ __forceinline__ float bf2f(unsigned short b) {
  return __uint_as_float(((unsigned)b) << 16);
}

static __device__ __forceinline__ unsigned cvtpk_bf16(float a, float b) {
  unsigned r;
  asm("v_cvt_pk_bf16_f32 %0, %1, %2" : "=v"(r) : "v"(a), "v"(b));
  return r;
}

static __device__ __forceinline__ f32x4 ntload4(const float* p) {
  return __builtin_nontemporal_load((const f32x4*)p);
}

// ---------------- merged: prep (blocks 0..2047) + pool pass 1 (2048..3071) ----
// prep: W -> Wt[h][kk][col][k'] bf16 (fragment-matched), cbuf = -8*softplus(ap).
// pool1: per (b,head,chunk-of-128-rows) online softmax partials over h.
// h and w1/w2 are read-once streams -> NON-TEMPORAL loads (preserve x in L3).
__global__ __launch_bounds__(256) void prep_pool_kernel(
    const float* __restrict__ w1, const float* __restrict__ w2,
    const float* __restrict__ ap, unsigned short* __restrict__ wt1,
    unsigned short* __restrict__ wt2, float* __restrict__ cbuf,
    const float* __restrict__ hin, float* __restrict__ part_o,
    float* __restrict__ part_ml) {
  int blk = blockIdx.x;
  int tid = threadIdx.x;
  if (blk < 2048) {
    int gid = blk * 256 + tid;  // 0..524287
    if (gid < DMODEL) {
      cbuf[gid] = -8.0f * log1pf(__expf(ap[gid]));
    }
    int h  = gid >> 16;
    int kk = (gid >> 13) & 7;   // K-tile index (32 k each)
    int c  = (gid >> 5) & 255;  // output col (n)
    int kp = gid & 31;          // k within tile
    int src = h * 65536 + (kk * 32 + kp) * 256 + c;
    wt1[gid] = f2bf(__builtin_nontemporal_load(w1 + src));
    wt2[gid] = f2bf(__builtin_nontemporal_load(w2 + src));
    return;
  }
  int bid = blk - 2048;  // 0..1023
  int chunk = bid & 63;
  int bh = bid >> 6;
  int head = bh & 7;
  int b = bh >> 3;
  int wv = tid >> 6, lane = tid & 63;
  int t0 = chunk * 128 + wv * 32;
  const float* hp = hin + ((size_t)(b * T_SEQ + t0)) * DMODEL + head * DH + lane * 4;

  float m = -1e30f, l = 0.f;
  float ox = 0.f, oy = 0.f, oz = 0.f, ow = 0.f;
  f32x4 hv = ntload4(hp);
  for (int r = 0; r < 32; ++r) {
    f32x4 cur = hv;
    if (r < 31) hv = ntload4(hp + (size_t)(r + 1) * DMODEL);
    float s = cur.x + cur.y + cur.z + cur.w;
    s += __shfl_xor(s, 32); s += __shfl_xor(s, 16); s += __shfl_xor(s, 8);
    s += __shfl_xor(s, 4);  s += __shfl_xor(s, 2);  s += __shfl_xor(s, 1);
    float logit = s * (1.0f / 256.0f);
    float mn = fmaxf(m, logit);
    float corr = __expf(m - mn);
    float p = __expf(logit - mn);
    l = l * corr + p;
    ox = ox * corr + p * cur.x;
    oy = oy * corr + p * cur.y;
    oz = oz * corr + p * cur.z;
    ow = ow * corr + p * cur.w;
    m = mn;
  }
  __shared__ __align__(16) float smO[4][256];
  __shared__ float smM[4], smL[4];
  {
    f32x4 ov; ov.x = ox; ov.y = oy; ov.z = oz; ov.w = ow;
    *(f32x4*)&smO[wv][lane * 4] = ov;
    if (lane == 0) { smM[wv] = m; smL[wv] = l; }
  }
  __syncthreads();
  if (tid < 64) {
    float M = fmaxf(fmaxf(smM[0], smM[1]), fmaxf(smM[2], smM[3]));
    float L = 0.f;
    f32x4 oc; oc.x = 0.f; oc.y = 0.f; oc.z = 0.f; oc.w = 0.f;
    #pragma unroll
    for (int w = 0; w < 4; ++w) {
      float wg = __expf(smM[w] - M);
      L += smL[w] * wg;
      f32x4 t = *(const f32x4*)&smO[w][tid * 4];
      oc.x += wg * t.x; oc.y += wg * t.y; oc.z += wg * t.z; oc.w += wg * t.w;
    }
    *(f32x4*)(part_o + (size_t)bid * 256 + tid * 4) = oc;
    if (tid == 0) { part_ml[bid * 2] = M; part_ml[bid * 2 + 1] = L; }
  }
}

// ---------------- pool pass 2: combine 64 chunk-partials per (b,head) --------
__global__ __launch_bounds__(256) void pool_combine_kernel(
    const float* __restrict__ part_o, const float* __restrict__ part_ml,
    float* __restrict__ pooled) {
  int bh = blockIdx.x;  // 16
  int tid = threadIdx.x;
  __shared__ float sm[64], sl[64];
  if (tid < 64) {
    sm[tid] = part_ml[(bh * 64 + tid) * 2];
    sl[tid] = part_ml[(bh * 64 + tid) * 2 + 1];
  }
  __syncthreads();
  float M = -1e30f;
  for (int c = 0; c < 64; ++c) M = fmaxf(M, sm[c]);
  float L = 0.f, o = 0.f;
  for (int c = 0; c < 64; ++c) {
    float wg = __expf(sm[c] - M);
    L += sl[c] * wg;
    o += wg * part_o[(size_t)(bh * 64 + c) * 256 + tid];
  }
  pooled[(bh >> 3) * DMODEL + (bh & 7) * DH + tid] = o / L;
}

// ---------------- main: 2 block-diag GEMMs (bf16 MFMA) + fused epilogue ------
// R16 structure (best: 112.8 us total). 512 threads = 8 waves; tile 64 rows x
// 256 cols (full head). Vectorized cvt_pk stage; fragment-matched W loads;
// LDS-staged output with NON-TEMPORAL stores. x loads stay temporal (L3 reuse
// across graph replays).
#define OBSTRIDE 260  // floats; 64*260*4 = 66560 B LDS
__global__ __launch_bounds__(512, 4) void main_kernel(
    const float* __restrict__ x, const unsigned short* __restrict__ wt1,
    const unsigned short* __restrict__ wt2, const float* __restrict__ b1,
    const float* __restrict__ b2, const float* __restrict__ cbuf,
    const float* __restrict__ pooled, float* __restrict__ out) {
  int bid = blockIdx.x;       // 8 heads * 256 mtiles
  int head = bid >> 8;
  int mt = bid & 255;
  int m0 = mt * 64;
  int bb = mt >> 7;           // batch index (m0 >= 8192 ?)
  int tid = threadIdx.x;
  int lane = tid & 63;
  int wv = tid >> 6;          // 0..7

  __shared__ __align__(16) char lds[64 * OBSTRIDE * 4];  // 65 KB, dual-use
  char* xls = lds;            // first 32 KB: bf16 x tile, XOR-swizzled
  float* obuf = (float*)lds;  // full 65 KB: f32 out tile (after sync)

  // stage x tile [64][256] f32 -> bf16 LDS; 4 iters, 16B unit per thread
  const float* xbase = x + (size_t)m0 * DMODEL + head * DH;
  #pragma unroll
  for (int i = 0; i < 4; ++i) {
    int f = tid + i * 512;      // 16B-unit index, 0..2047
    int row = f >> 5, u8 = f & 31;
    const float* src = xbase + (size_t)row * DMODEL + u8 * 8;
    f32x4 lo = *(const f32x4*)src;
    f32x4 hi = *(const f32x4*)(src + 4);
    union { unsigned u[4]; short8 s; } pk;
    pk.u[0] = cvtpk_bf16(lo.x, lo.y);
    pk.u[1] = cvtpk_bf16(lo.z, lo.w);
    pk.u[2] = cvtpk_bf16(hi.x, hi.y);
    pk.u[3] = cvtpk_bf16(hi.z, hi.w);
    int byte = (row * 512 + u8 * 16) ^ ((row & 7) << 4);  // G4 swizzle
    *(short8*)(xls + byte) = pk.s;
  }
  __syncthreads();

  f32x4 acc1[4][2], acc2[4][2];
  #pragma unroll
  for (int mi = 0; mi < 4; ++mi)
    #pragma unroll
    for (int ni = 0; ni < 2; ++ni) {
      acc1[mi][ni] = (f32x4){0.f, 0.f, 0.f, 0.f};
      acc2[mi][ni] = (f32x4){0.f, 0.f, 0.f, 0.f};
    }

  int n0 = wv * 32;
  int r16 = lane & 15, kq = lane >> 4;
  const unsigned short* w1h = wt1 + head * 65536;
  const unsigned short* w2h = wt2 + head * 65536;

  #pragma unroll
  for (int kk = 0; kk < 8; ++kk) {
    int k0 = kk * 32;
    short8 af[4], bf1[2], bf2[2];
    #pragma unroll
    for (int mi = 0; mi < 4; ++mi) {
      int row = mi * 16 + r16;
      int byte = row * 512 + (k0 + kq * 8) * 2;
      byte ^= (row & 7) << 4;
      af[mi] = *(const short8*)(xls + byte);
    }
    #pragma unroll
    for (int ni = 0; ni < 2; ++ni) {
      // Wt[h][kk][col][k']: wave reads 1KB contiguous per fragment
      int col = n0 + ni * 16 + r16;
      size_t off = (size_t)kk * 8192 + col * 32 + kq * 8;
      bf1[ni] = *(const short8*)(w1h + off);
      bf2[ni] = *(const short8*)(w2h + off);
    }
    // Swapped operands: D = W_asA . x_asB -> lane holds 4 consecutive output
    // cols at one output row.
    #pragma unroll
    for (int mi = 0; mi < 4; ++mi)
      #pragma unroll
      for (int ni = 0; ni < 2; ++ni) {
        acc1[mi][ni] = __builtin_amdgcn_mfma_f32_16x16x32_bf16(bf1[ni], af[mi], acc1[mi][ni], 0, 0, 0);
        acc2[mi][ni] = __builtin_amdgcn_mfma_f32_16x16x32_bf16(bf2[ni], af[mi], acc2[mi][ni], 0, 0, 0);
      }
  }

  // pull this thread's epilogue x (bf16) out of xls BEFORE obuf overwrites it
  short4v xb[2][4];
  #pragma unroll
  for (int ni = 0; ni < 2; ++ni) {
    int cFull = n0 + ni * 16 + kq * 4;  // 4 consecutive cols, 8B aligned
    #pragma unroll
    for (int mi = 0; mi < 4; ++mi) {
      int row = mi * 16 + r16;
      int byte = row * 512 + cFull * 2;
      byte ^= (row & 7) << 4;
      xb[ni][mi] = *(const short4v*)(xls + byte);
    }
  }
  __syncthreads();  // all xls reads done; safe to overwrite with obuf

  // epilogue: fragment (mi,ni) -> row mi*16+r16, cols n0+ni*16+kq*4+{0..3}
  #pragma unroll
  for (int ni = 0; ni < 2; ++ni) {
    int ncol = n0 + ni * 16 + kq * 4;          // 0..255 within head
    int d = head * DH + ncol;
    f32x4 b1v = *(const f32x4*)(b1 + d);
    f32x4 b2v = *(const f32x4*)(b2 + d);
    f32x4 cdv = *(const f32x4*)(cbuf + d);
    f32x4 plv = *(const f32x4*)(pooled + bb * DMODEL + d);
    #pragma unroll
    for (int mi = 0; mi < 4; ++mi) {
      int row = mi * 16 + r16;
      f32x4 o;
      #pragma unroll
      for (int r = 0; r < 4; ++r) {
        float y1 = acc1[mi][ni][r] + b1v[r];
        float y2 = acc2[mi][ni][r] + b2v[r];
        // fast sigmoid: v_exp + v_rcp (single instrs, ~2.5ulp)
        float gx = __builtin_amdgcn_rcpf(1.0f + __expf(-y1));
        float ga = __builtin_amdgcn_rcpf(1.0f + __expf(-y2));
        float la = cdv[r] * ga;              // log_a
        float av = __expf(la);               // a
        float sq = __builtin_amdgcn_sqrtf(fmaxf(1.0f - av * av, 0.0f));
        float xv = bf2f((unsigned short)xb[ni][mi][r]);
        o[r] = av * plv[r] + xv * gx * sq;
      }
      *(f32x4*)(obuf + row * OBSTRIDE + ncol) = o;
    }
  }
  __syncthreads();

  // coalesced NON-TEMPORAL store: full 128B lines, bypass L2/L3 retention
  float* obase = out + (size_t)m0 * DMODEL + head * DH;
  #pragma unroll
  for (int i = 0; i < 8; ++i) {
    int u = tid + i * 512;
    int row = u >> 6, c4 = u & 63;
    f32x4 val = *(const f32x4*)(obuf + row * OBSTRIDE + c4 * 4);
    __builtin_nontemporal_store(val, (f32x4*)(obase + (size_t)row * DMODEL + c4 * 4));
  }
}

extern "C" void kernel_launch(void* const* d_in, const int* in_sizes, int n_in,
                              void* d_out, int out_size, void* d_ws, size_t ws_size,
                              hipStream_t stream) {
  const float* x  = (const float*)d_in[0];
  const float* h  = (const float*)d_in[1];
  const float* w1 = (const float*)d_in[2];
  const float* b1 = (const float*)d_in[3];
  const float* w2 = (const float*)d_in[4];
  const float* b2 = (const float*)d_in[5];
  const float* ap = (const float*)d_in[6];
  float* out = (float*)d_out;

  char* ws = (char*)d_ws;
  unsigned short* wt1 = (unsigned short*)ws;                     // 1 MB
  unsigned short* wt2 = (unsigned short*)(ws + (1u << 20));      // 1 MB
  float* cbuf    = (float*)(ws + (2u << 20));                    // 8 KB
  float* pooled  = (float*)(ws + (2u << 20) + 8192);             // 16 KB
  float* part_ml = (float*)(ws + (2u << 20) + 24576);            // 8 KB
  float* part_o  = (float*)(ws + (2u << 20) + 32768);            // 1 MB

  prep_pool_kernel<<<dim3(3072), dim3(256), 0, stream>>>(
      w1, w2, ap, wt1, wt2, cbuf, h, part_o, part_ml);
  pool_combine_kernel<<<dim3(16), dim3(256), 0, stream>>>(part_o, part_ml, pooled);
  main_kernel<<<dim3(2048), dim3(512), 0, stream>>>(x, wt1, wt2, b1, b2, cbuf, pooled, out);
}

// Round 18
// 112.678 us; speedup vs baseline: 1.0520x; 1.0520x over previous
//
#include <hip/hip_runtime.h>

#define T_SEQ 8192
#define BATCH 2
#define DMODEL 2048
#define NHEADS 8
#define DH 256
#define NROWS (BATCH * T_SEQ)  // 16384

typedef __attribute__((ext_vector_type(8))) short short8;
typedef __attribute__((ext_vector_type(4))) short short4v;
typedef __attribute__((ext_vector_type(4))) float f32x4;

static __device__ __forceinline__ unsigned short f2bf(float f) {
  unsigned u = __float_as_uint(f);
  unsigned r = u + 0x7FFFu + ((u >> 16) & 1u);  // RNE
  return (unsigned short)(r >> 16);
}

static __device__ __forceinline__ float bf2f(unsigned short b) {
  return __uint_as_float(((unsigned)b) << 16);
}

static __device__ __forceinline__ unsigned cvtpk_bf16(float a, float b) {
  unsigned r;
  asm("v_cvt_pk_bf16_f32 %0, %1, %2" : "=v"(r) : "v"(a), "v"(b));
  return r;
}

// ---------------- merged: prep (blocks 0..2047) + pool pass 1 (2048..3071) ----
// prep: W -> Wt[h][kk][col][k'] bf16 (fragment-matched; wave W-load = 1KB
// contiguous), cbuf[d] = -8*softplus(a_param[d]).
// pool1: per (b,head,chunk-of-128-rows) online softmax partials over h.
__global__ __launch_bounds__(256) void prep_pool_kernel(
    const float* __restrict__ w1, const float* __restrict__ w2,
    const float* __restrict__ ap, unsigned short* __restrict__ wt1,
    unsigned short* __restrict__ wt2, float* __restrict__ cbuf,
    const float* __restrict__ hin, float* __restrict__ part_o,
    float* __restrict__ part_ml) {
  int blk = blockIdx.x;
  int tid = threadIdx.x;
  if (blk < 2048) {
    int gid = blk * 256 + tid;  // 0..524287
    if (gid < DMODEL) {
      cbuf[gid] = -8.0f * log1pf(__expf(ap[gid]));
    }
    int h  = gid >> 16;
    int kk = (gid >> 13) & 7;   // K-tile index (32 k each)
    int c  = (gid >> 5) & 255;  // output col (n)
    int kp = gid & 31;          // k within tile
    int src = h * 65536 + (kk * 32 + kp) * 256 + c;
    wt1[gid] = f2bf(w1[src]);
    wt2[gid] = f2bf(w2[src]);
    return;
  }
  int bid = blk - 2048;  // 0..1023
  int chunk = bid & 63;
  int bh = bid >> 6;
  int head = bh & 7;
  int b = bh >> 3;
  int wv = tid >> 6, lane = tid & 63;
  int t0 = chunk * 128 + wv * 32;
  const float* hp = hin + ((size_t)(b * T_SEQ + t0)) * DMODEL + head * DH + lane * 4;

  float m = -1e30f, l = 0.f;
  float ox = 0.f, oy = 0.f, oz = 0.f, ow = 0.f;
  f32x4 hv = *(const f32x4*)hp;
  for (int r = 0; r < 32; ++r) {
    f32x4 cur = hv;
    if (r < 31) hv = *(const f32x4*)(hp + (size_t)(r + 1) * DMODEL);
    float s = cur.x + cur.y + cur.z + cur.w;
    s += __shfl_xor(s, 32); s += __shfl_xor(s, 16); s += __shfl_xor(s, 8);
    s += __shfl_xor(s, 4);  s += __shfl_xor(s, 2);  s += __shfl_xor(s, 1);
    float logit = s * (1.0f / 256.0f);
    float mn = fmaxf(m, logit);
    float corr = __expf(m - mn);
    float p = __expf(logit - mn);
    l = l * corr + p;
    ox = ox * corr + p * cur.x;
    oy = oy * corr + p * cur.y;
    oz = oz * corr + p * cur.z;
    ow = ow * corr + p * cur.w;
    m = mn;
  }
  __shared__ __align__(16) float smO[4][256];
  __shared__ float smM[4], smL[4];
  {
    f32x4 ov; ov.x = ox; ov.y = oy; ov.z = oz; ov.w = ow;
    *(f32x4*)&smO[wv][lane * 4] = ov;
    if (lane == 0) { smM[wv] = m; smL[wv] = l; }
  }
  __syncthreads();
  if (tid < 64) {
    float M = fmaxf(fmaxf(smM[0], smM[1]), fmaxf(smM[2], smM[3]));
    float L = 0.f;
    f32x4 oc; oc.x = 0.f; oc.y = 0.f; oc.z = 0.f; oc.w = 0.f;
    #pragma unroll
    for (int w = 0; w < 4; ++w) {
      float wg = __expf(smM[w] - M);
      L += smL[w] * wg;
      f32x4 t = *(const f32x4*)&smO[w][tid * 4];
      oc.x += wg * t.x; oc.y += wg * t.y; oc.z += wg * t.z; oc.w += wg * t.w;
    }
    *(f32x4*)(part_o + (size_t)bid * 256 + tid * 4) = oc;
    if (tid == 0) { part_ml[bid * 2] = M; part_ml[bid * 2 + 1] = L; }
  }
}

// ---------------- pool pass 2: combine 64 chunk-partials per (b,head) --------
__global__ __launch_bounds__(256) void pool_combine_kernel(
    const float* __restrict__ part_o, const float* __restrict__ part_ml,
    float* __restrict__ pooled) {
  int bh = blockIdx.x;  // 16
  int tid = threadIdx.x;
  __shared__ float sm[64], sl[64];
  if (tid < 64) {
    sm[tid] = part_ml[(bh * 64 + tid) * 2];
    sl[tid] = part_ml[(bh * 64 + tid) * 2 + 1];
  }
  __syncthreads();
  float M = -1e30f;
  for (int c = 0; c < 64; ++c) M = fmaxf(M, sm[c]);
  float L = 0.f, o = 0.f;
  for (int c = 0; c < 64; ++c) {
    float wg = __expf(sm[c] - M);
    L += sl[c] * wg;
    o += wg * part_o[(size_t)(bh * 64 + c) * 256 + tid];
  }
  pooled[(bh >> 3) * DMODEL + (bh & 7) * DH + tid] = o / L;
}

// ---------------- main: 2 block-diag GEMMs (bf16 MFMA) + fused epilogue ------
// R16 structure (best measured: 112.8 us total). 512 threads = 8 waves; tile
// 64 rows x 256 cols (full head). Vectorized cvt_pk stage; fragment-matched W
// loads; LDS-staged output with NON-TEMPORAL stores (out is streaming; keep
// Wt/x resident in L2/L3).
#define OBSTRIDE 260  // floats; 64*260*4 = 66560 B LDS
__global__ __launch_bounds__(512, 4) void main_kernel(
    const float* __restrict__ x, const unsigned short* __restrict__ wt1,
    const unsigned short* __restrict__ wt2, const float* __restrict__ b1,
    const float* __restrict__ b2, const float* __restrict__ cbuf,
    const float* __restrict__ pooled, float* __restrict__ out) {
  int bid = blockIdx.x;       // 8 heads * 256 mtiles
  int head = bid >> 8;
  int mt = bid & 255;
  int m0 = mt * 64;
  int bb = mt >> 7;           // batch index (m0 >= 8192 ?)
  int tid = threadIdx.x;
  int lane = tid & 63;
  int wv = tid >> 6;          // 0..7

  __shared__ __align__(16) char lds[64 * OBSTRIDE * 4];  // 65 KB, dual-use
  char* xls = lds;            // first 32 KB: bf16 x tile, XOR-swizzled
  float* obuf = (float*)lds;  // full 65 KB: f32 out tile (after sync)

  // stage x tile [64][256] f32 -> bf16 LDS; 4 iters, 16B unit per thread
  const float* xbase = x + (size_t)m0 * DMODEL + head * DH;
  #pragma unroll
  for (int i = 0; i < 4; ++i) {
    int f = tid + i * 512;      // 16B-unit index, 0..2047
    int row = f >> 5, u8 = f & 31;
    const float* src = xbase + (size_t)row * DMODEL + u8 * 8;
    f32x4 lo = *(const f32x4*)src;
    f32x4 hi = *(const f32x4*)(src + 4);
    union { unsigned u[4]; short8 s; } pk;
    pk.u[0] = cvtpk_bf16(lo.x, lo.y);
    pk.u[1] = cvtpk_bf16(lo.z, lo.w);
    pk.u[2] = cvtpk_bf16(hi.x, hi.y);
    pk.u[3] = cvtpk_bf16(hi.z, hi.w);
    int byte = (row * 512 + u8 * 16) ^ ((row & 7) << 4);  // G4 swizzle
    *(short8*)(xls + byte) = pk.s;
  }
  __syncthreads();

  f32x4 acc1[4][2], acc2[4][2];
  #pragma unroll
  for (int mi = 0; mi < 4; ++mi)
    #pragma unroll
    for (int ni = 0; ni < 2; ++ni) {
      acc1[mi][ni] = (f32x4){0.f, 0.f, 0.f, 0.f};
      acc2[mi][ni] = (f32x4){0.f, 0.f, 0.f, 0.f};
    }

  int n0 = wv * 32;
  int r16 = lane & 15, kq = lane >> 4;
  const unsigned short* w1h = wt1 + head * 65536;
  const unsigned short* w2h = wt2 + head * 65536;

  #pragma unroll
  for (int kk = 0; kk < 8; ++kk) {
    int k0 = kk * 32;
    short8 af[4], bf1[2], bf2[2];
    #pragma unroll
    for (int mi = 0; mi < 4; ++mi) {
      int row = mi * 16 + r16;
      int byte = row * 512 + (k0 + kq * 8) * 2;
      byte ^= (row & 7) << 4;
      af[mi] = *(const short8*)(xls + byte);
    }
    #pragma unroll
    for (int ni = 0; ni < 2; ++ni) {
      // Wt[h][kk][col][k']: wave reads 1KB contiguous per fragment
      int col = n0 + ni * 16 + r16;
      size_t off = (size_t)kk * 8192 + col * 32 + kq * 8;
      bf1[ni] = *(const short8*)(w1h + off);
      bf2[ni] = *(const short8*)(w2h + off);
    }
    // Swapped operands: D = W_asA . x_asB -> lane holds 4 consecutive output
    // cols at one output row.
    #pragma unroll
    for (int mi = 0; mi < 4; ++mi)
      #pragma unroll
      for (int ni = 0; ni < 2; ++ni) {
        acc1[mi][ni] = __builtin_amdgcn_mfma_f32_16x16x32_bf16(bf1[ni], af[mi], acc1[mi][ni], 0, 0, 0);
        acc2[mi][ni] = __builtin_amdgcn_mfma_f32_16x16x32_bf16(bf2[ni], af[mi], acc2[mi][ni], 0, 0, 0);
      }
  }

  // pull this thread's epilogue x (bf16) out of xls BEFORE obuf overwrites it
  short4v xb[2][4];
  #pragma unroll
  for (int ni = 0; ni < 2; ++ni) {
    int cFull = n0 + ni * 16 + kq * 4;  // 4 consecutive cols, 8B aligned
    #pragma unroll
    for (int mi = 0; mi < 4; ++mi) {
      int row = mi * 16 + r16;
      int byte = row * 512 + cFull * 2;
      byte ^= (row & 7) << 4;
      xb[ni][mi] = *(const short4v*)(xls + byte);
    }
  }
  __syncthreads();  // all xls reads done; safe to overwrite with obuf

  // epilogue: fragment (mi,ni) -> row mi*16+r16, cols n0+ni*16+kq*4+{0..3}
  #pragma unroll
  for (int ni = 0; ni < 2; ++ni) {
    int ncol = n0 + ni * 16 + kq * 4;          // 0..255 within head
    int d = head * DH + ncol;
    f32x4 b1v = *(const f32x4*)(b1 + d);
    f32x4 b2v = *(const f32x4*)(b2 + d);
    f32x4 cdv = *(const f32x4*)(cbuf + d);
    f32x4 plv = *(const f32x4*)(pooled + bb * DMODEL + d);
    #pragma unroll
    for (int mi = 0; mi < 4; ++mi) {
      int row = mi * 16 + r16;
      f32x4 o;
      #pragma unroll
      for (int r = 0; r < 4; ++r) {
        float y1 = acc1[mi][ni][r] + b1v[r];
        float y2 = acc2[mi][ni][r] + b2v[r];
        // fast sigmoid: v_exp + v_rcp (single instrs, ~2.5ulp)
        float gx = __builtin_amdgcn_rcpf(1.0f + __expf(-y1));
        float ga = __builtin_amdgcn_rcpf(1.0f + __expf(-y2));
        float la = cdv[r] * ga;              // log_a
        float av = __expf(la);               // a
        float sq = __builtin_amdgcn_sqrtf(fmaxf(1.0f - av * av, 0.0f));
        float xv = bf2f((unsigned short)xb[ni][mi][r]);
        o[r] = av * plv[r] + xv * gx * sq;
      }
      *(f32x4*)(obuf + row * OBSTRIDE + ncol) = o;
    }
  }
  __syncthreads();

  // coalesced NON-TEMPORAL store: full 128B lines, bypass L2/L3 retention
  float* obase = out + (size_t)m0 * DMODEL + head * DH;
  #pragma unroll
  for (int i = 0; i < 8; ++i) {
    int u = tid + i * 512;
    int row = u >> 6, c4 = u & 63;
    f32x4 val = *(const f32x4*)(obuf + row * OBSTRIDE + c4 * 4);
    __builtin_nontemporal_store(val, (f32x4*)(obase + (size_t)row * DMODEL + c4 * 4));
  }
}

extern "C" void kernel_launch(void* const* d_in, const int* in_sizes, int n_in,
                              void* d_out, int out_size, void* d_ws, size_t ws_size,
                              hipStream_t stream) {
  const float* x  = (const float*)d_in[0];
  const float* h  = (const float*)d_in[1];
  const float* w1 = (const float*)d_in[2];
  const float* b1 = (const float*)d_in[3];
  const float* w2 = (const float*)d_in[4];
  const float* b2 = (const float*)d_in[5];
  const float* ap = (const float*)d_in[6];
  float* out = (float*)d_out;

  char* ws = (char*)d_ws;
  unsigned short* wt1 = (unsigned short*)ws;                     // 1 MB
  unsigned short* wt2 = (unsigned short*)(ws + (1u << 20));      // 1 MB
  float* cbuf    = (float*)(ws + (2u << 20));                    // 8 KB
  float* pooled  = (float*)(ws + (2u << 20) + 8192);             // 16 KB
  float* part_ml = (float*)(ws + (2u << 20) + 24576);            // 8 KB
  float* part_o  = (float*)(ws + (2u << 20) + 32768);            // 1 MB

  prep_pool_kernel<<<dim3(3072), dim3(256), 0, stream>>>(
      w1, w2, ap, wt1, wt2, cbuf, h, part_o, part_ml);
  pool_combine_kernel<<<dim3(16), dim3(256), 0, stream>>>(part_o, part_ml, pooled);
  main_kernel<<<dim3(2048), dim3(512), 0, stream>>>(x, wt1, wt2, b1, b2, cbuf, pooled, out);
}